// Round 1
// 155.492 us; speedup vs baseline: 1.0578x; 1.0578x over previous
//
#include <hip/hip_runtime.h>
#include <hip/hip_bf16.h>
#include <cstdint>
#include <cstddef>

typedef short short8 __attribute__((ext_vector_type(8)));
typedef float f32x4 __attribute__((ext_vector_type(4)));
typedef float f32x2 __attribute__((ext_vector_type(2)));

#define NS    2048
#define KPAD  288
#define H2    512
#define HID   256
#define WPB   7       // windows per sig workgroup (192 thr = 3 waves = 3 thirds)
#define SBLK  293     // ceil(2048/7)

#define MFMA(a,b,c) __builtin_amdgcn_mfma_f32_16x16x32_bf16((a),(b),(c),0,0,0)

__device__ __forceinline__ void gl2lds16(const void* g, void* l) {
    __builtin_amdgcn_global_load_lds(
        (const __attribute__((address_space(1))) void*)g,
        (__attribute__((address_space(3))) void*)l, 16, 0, 0);
}
__device__ __forceinline__ float geluf(float x) {
    return 0.5f * x * (1.0f + erff(x * 0.70710678118654752f));
}
__device__ __forceinline__ f32x4 shfl4(f32x4 v, int d) {
    f32x4 r;
    r[0] = __shfl_xor(v[0], d); r[1] = __shfl_xor(v[1], d);
    r[2] = __shfl_xor(v[2], d); r[3] = __shfl_xor(v[3], d);
    return r;
}

struct Tbl3 { short col[729]; };
static constexpr Tbl3 make_tbl3() {
    Tbl3 t{};
    for (int x = 0; x < 729; ++x) t.col[x] = -1;
    int r = 0;
    for (int i = 0; i < 9; ++i)
        for (int j = 0; j < 9; ++j)
            for (int k = 0; k < 9; ++k) {
                bool lt1 = (i < j) || (i == j && (j < k || (j == k && k < i)));
                bool lt2 = (i < k) || (i == k && (j < i || (j == i && k < j)));
                if (lt1 && lt2) { t.col[(i*9+j)*9+k] = (short)(45 + r); ++r; }
            }
    return t;
}
static constexpr Tbl3 TBL3 = make_tbl3();

// ============================================================================
// sig: unchanged this round (control). LDS+latency bound, 48.3us measured.
// ============================================================================
#define SIG_STEP(VA_,VB_,VC_) { \
    const float hh = 0.5f * S1i + vi * (1.0f/6.0f); \
    const float ra = S2ra + hh * (VA_); \
    const float rb = S2rb + hh * (VB_); \
    const float rc = S2rc + hh * (VC_); \
    const f32x2 ra2 = {ra, ra}, rb2 = {rb, rb}, rc2 = {rc, rc}; \
    S3sa += ra * v0; S3pa0 += ra2*vp0; S3pa1 += ra2*vp1; S3pa2 += ra2*vp2; S3pa3 += ra2*vp3; \
    S3sb += rb * v0; S3pb0 += rb2*vp0; S3pb1 += rb2*vp1; S3pb2 += rb2*vp2; S3pb3 += rb2*vp3; \
    S3sc += rc * v0; S3pc0 += rc2*vp0; S3pc1 += rc2*vp1; S3pc2 += rc2*vp2; S3pc3 += rc2*vp3; \
    const float aa = S1i + 0.5f * vi; \
    S2ra += aa * (VA_); S2rb += aa * (VB_); S2rc += aa * (VC_); \
    S1i += vi; }

#define SIG_MAIN(VA_,VB_,VC_) { \
    { const float* xr = &X[(g0 - lo) * 8]; \
      const float4 e0 = *(const float4*)xr; \
      const float4 e1 = *(const float4*)(xr + 4); \
      const float rs = xr[ioff]; \
      const float v0 = 0.0f; \
      const f32x2 vp0 = {e0.x, e0.y}, vp1 = {e0.z, e0.w}, vp2 = {e1.x, e1.y}, vp3 = {e1.z, e1.w}; \
      const float vi = (ci == 0) ? 0.0f : rs; \
      SIG_STEP(VA_,VB_,VC_) } \
    const float* pd = &PD[(sm59 + 1 - lo + 59) * 8]; \
    float4 d0 = *(const float4*)pd; \
    float4 d1 = *(const float4*)(pd + 4); \
    float rn = pd[ioff]; \
    _Pragma("unroll 2") \
    for (int j = 1; j < 60; ++j) { \
      const float4 e0 = d0; const float4 e1 = d1; const float rs = rn; \
      pd += 8; \
      d0 = *(const float4*)pd; d1 = *(const float4*)(pd + 4); rn = pd[ioff]; \
      const float v0 = DT; \
      const f32x2 vp0 = {e0.x, e0.y}, vp1 = {e0.z, e0.w}, vp2 = {e1.x, e1.y}, vp3 = {e1.z, e1.w}; \
      const float vi = (ci == 0) ? DT : rs; \
      SIG_STEP(VA_,VB_,VC_) \
    } }

#define SIG_ST(RA,RB,RC) \
    if (act) { \
        if ((RA) == 0) S1buf[widx * 9 + ci] = S1i; \
        float* sb = &S2buf[widx * 81 + ci * 9]; \
        sb[RA] = S2ra; sb[RB] = S2rb; sb[RC] = S2rc; \
    }

#define S3EL0(SL) S3s##SL
#define S3EL1(SL) S3p##SL##0[0]
#define S3EL2(SL) S3p##SL##0[1]
#define S3EL3(SL) S3p##SL##1[0]
#define S3EL4(SL) S3p##SL##1[1]
#define S3EL5(SL) S3p##SL##2[0]
#define S3EL6(SL) S3p##SL##2[1]
#define S3EL7(SL) S3p##SL##3[0]
#define S3EL8(SL) S3p##SL##3[1]

#define SIG_E2(SL,J2) if (ci < (J2)) { \
    const float val2 = S2r##SL - 0.5f * S1i * s1v##J2; \
    const int col2 = 9 + ci*8 - (ci*(ci-1))/2 + ((J2) - ci - 1); \
    frow[col2] = __float2bfloat16(val2); }

#define SIG_E3(SL,R,K) { const int col3 = TBL3.col[tb + (R)*9 + (K)]; \
    if (col3 >= 0) { \
        const float val3 = S3EL##K(SL) \
            - 0.5f * (S1i * S2w[(R)*9+(K)] + S2r##SL * s1v##K) \
            + S1i * s1v##R * s1v##K * (1.0f/3.0f); \
        frow[col3] = __float2bfloat16(val3); } }

#define SIG_E3R(SL,R) SIG_E3(SL,R,0) SIG_E3(SL,R,1) SIG_E3(SL,R,2) SIG_E3(SL,R,3) \
    SIG_E3(SL,R,4) SIG_E3(SL,R,5) SIG_E3(SL,R,6) SIG_E3(SL,R,7) SIG_E3(SL,R,8)

#define SIG_EMIT(RA,RB,RC) \
    if (act) { \
        if ((RA) == 0) { \
            frow[ci] = __float2bfloat16(S1i); \
            if (ci == 0) { \
                const __hip_bfloat16 z16 = __float2bfloat16(0.0f); \
                frow[285] = z16; frow[286] = z16; frow[287] = z16; \
            } \
        } \
        SIG_E2(a,RA) SIG_E2(b,RB) SIG_E2(c,RC) \
        SIG_E3R(a,RA) SIG_E3R(b,RB) SIG_E3R(c,RC) \
    }

__global__ __launch_bounds__(192) __attribute__((amdgpu_waves_per_eu(1, 6)))
void sig_kernel(const float* __restrict__ x, __hip_bfloat16* __restrict__ feats) {
    __shared__ __align__(16) float X[66 * 8];
    __shared__ __align__(16) float PD[126 * 8];   // rows 0..58 zero pad, 59+r = x[lo+r]-x[lo+r-1]
    __shared__ float S2buf[WPB * 81];
    __shared__ float S1buf[WPB * 9];

    const int blk = blockIdx.x;
    const int b   = blk / SBLK;
    const int s0  = (blk % SBLK) * WPB;
    const int lo  = (s0 - 59 > 0) ? (s0 - 59) : 0;
    const int hi  = (s0 + WPB - 1 < NS - 1) ? (s0 + WPB - 1) : (NS - 1);
    const int nrow = hi - lo + 1;     // <= 66
    const int tid = threadIdx.x;

    {   // stage x rows
        const float4* src = (const float4*)(x + ((size_t)b * NS + lo) * 8);
        float4* X4 = (float4*)X;
        const int n4 = nrow * 2;
        for (int t = tid; t < n4; t += 192) X4[t] = src[t];
    }
    __syncthreads();
    {   // build padded diff rows
        const float4* X4 = (const float4*)X;
        float4* PD4 = (float4*)PD;
        for (int t = tid; t < 252; t += 192) {
            const int p = t >> 1;         // padded row
            const int r = p - 59;         // diff row
            float4 dv = {0.f, 0.f, 0.f, 0.f};
            if (r > 0 && r < nrow) {
                const float4 a = X4[t - 118], bb = X4[t - 120];
                dv.x = a.x - bb.x; dv.y = a.y - bb.y; dv.z = a.z - bb.z; dv.w = a.w - bb.w;
            }
            PD4[t] = dv;
        }
    }
    __syncthreads();

    const int t3    = tid >> 6;           // third (wave-uniform): rows {0,1,2}/{3,4,5}/{6,7,8}
    const int lt    = tid & 63;
    const int widx0 = lt / 9;             // 0..7 (lane 63 idle)
    const int ci    = lt - widx0 * 9;     // slab index 0..8
    const bool act  = (lt < 63) && (s0 + widx0 < NS);
    const int widx  = (widx0 < WPB - 1) ? widx0 : WPB - 1;
    int s = s0 + widx; if (s > NS - 1) s = NS - 1;

    float S3sa=0.f, S3sb=0.f, S3sc=0.f;
    f32x2 S3pa0={0.f,0.f},S3pa1={0.f,0.f},S3pa2={0.f,0.f},S3pa3={0.f,0.f};
    f32x2 S3pb0={0.f,0.f},S3pb1={0.f,0.f},S3pb2={0.f,0.f},S3pb3={0.f,0.f};
    f32x2 S3pc0={0.f,0.f},S3pc1={0.f,0.f},S3pc2={0.f,0.f},S3pc3={0.f,0.f};
    float S2ra=0.f, S2rb=0.f, S2rc=0.f;
    float S1i = 0.f;
    const int ioff = (ci > 0) ? (ci - 1) : 0;
    const int sm59 = s - 59;
    const int g0   = (sm59 > 0) ? sm59 : 0;
    const float DT = 1.0f / 59.0f;

    if (t3 == 0)      { SIG_MAIN(v0,   e0.x, e0.y) }
    else if (t3 == 1) { SIG_MAIN(e0.z, e0.w, e1.x) }
    else              { SIG_MAIN(e1.y, e1.z, e1.w) }

    if (t3 == 0)      { SIG_ST(0,1,2) }
    else if (t3 == 1) { SIG_ST(3,4,5) }
    else              { SIG_ST(6,7,8) }
    __syncthreads();

    const float* s1p = &S1buf[widx * 9];
    const float s1v0=s1p[0], s1v1=s1p[1], s1v2=s1p[2], s1v3=s1p[3], s1v4=s1p[4];
    const float s1v5=s1p[5], s1v6=s1p[6], s1v7=s1p[7], s1v8=s1p[8];
    const float* S2w = &S2buf[widx * 81];
    const int tb = ci * 81;
    __hip_bfloat16* frow = feats + (size_t)(b * NS + s) * KPAD;

    if (t3 == 0)      { SIG_EMIT(0,1,2) }
    else if (t3 == 1) { SIG_EMIT(3,4,5) }
    else              { SIG_EMIT(6,7,8) }
}

// ============================================================================
// prep: fused convert_w1 + convert_w2g + stats-zero (was 3 launches incl memset)
// blocks 0..255   : w2g column n = blk       (512 thr, shfl+LDS reduce)
// blocks 256..767 : w1T row n = blk-256      (288 active thr) + zero 64 stats
// ============================================================================
__global__ __launch_bounds__(512)
void prep_kernel(const float* __restrict__ w1, const float* __restrict__ w2,
                 const float* __restrict__ lng, const float* __restrict__ lnb,
                 const float* __restrict__ b2,
                 __hip_bfloat16* __restrict__ w1T, __hip_bfloat16* __restrict__ w2g,
                 float* __restrict__ gw, float* __restrict__ cvec,
                 float* __restrict__ stats) {
    const int blk = blockIdx.x;
    if (blk < 256) {
        const int n = blk, k = threadIdx.x;
        const float wv = w2[(size_t)k * HID + n];
        const float a = lng[k] * wv;
        const float c = lnb[k] * wv;
        w2g[(size_t)n * H2 + k] = __float2bfloat16(a);
        float ra = a, rc = c;
#pragma unroll
        for (int d = 1; d < 64; d <<= 1) { ra += __shfl_xor(ra, d); rc += __shfl_xor(rc, d); }
        __shared__ float r1[8], r2[8];
        const int wv_ = k >> 6, ln = k & 63;
        if (ln == 0) { r1[wv_] = ra; r2[wv_] = rc; }
        __syncthreads();
        if (k == 0) {
            float sa = 0.f, sc = 0.f;
#pragma unroll
            for (int i = 0; i < 8; ++i) { sa += r1[i]; sc += r2[i]; }
            gw[n] = sa; cvec[n] = sc + b2[n];
        }
    } else {
        const int n = blk - 256;           // 0..511
        const int k = threadIdx.x;
        if (k < KPAD) {
            const float v = (k < 285) ? w1[(size_t)k * H2 + n] : 0.0f;
            w1T[(size_t)n * KPAD + k] = __float2bfloat16(v);
        }
        if (k < 64) stats[n * 64 + k] = 0.0f;   // 512*64 = 32768 floats
    }
}

// ============================================================================
// GEMM core: 128x128 tile, 256 thr / 4 waves, wave tile 64x64.
// NEW: 2-phase double-buffered LDS staging (T3-minimal). Next K-tile's
// global_load_lds is issued BEFORE the ds_read+MFMA of the current tile, so
// the barrier drain at the end of the step overlaps ~200-300cy of compute
// instead of exposing the full load latency on every one of the 9/16 K-steps.
// ============================================================================
#define GDECL \
    f32x4 acc00={0,0,0,0},acc01={0,0,0,0},acc02={0,0,0,0},acc03={0,0,0,0}; \
    f32x4 acc10={0,0,0,0},acc11={0,0,0,0},acc12={0,0,0,0},acc13={0,0,0,0}; \
    f32x4 acc20={0,0,0,0},acc21={0,0,0,0},acc22={0,0,0,0},acc23={0,0,0,0}; \
    f32x4 acc30={0,0,0,0},acc31={0,0,0,0},acc32={0,0,0,0},acc33={0,0,0,0};

#define GMROW(mf) { const short8 av = *(const short8*)(abase + (mf)*512); \
    acc##mf##0 = MFMA(av, b0v, acc##mf##0); acc##mf##1 = MFMA(av, b1v, acc##mf##1); \
    acc##mf##2 = MFMA(av, b2v, acc##mf##2); acc##mf##3 = MFMA(av, b3v, acc##mf##3); }

#define GSTAGE(APTR, BPTR, KD, K0, LA, LB) { \
    int c = tid; \
    gl2lds16((APTR) + (size_t)(m0 + (c>>2))*(KD) + (K0) + (c&3)*8, (char*)(LA) + (c & ~63)*16); \
    gl2lds16((BPTR) + (size_t)(n0 + (c>>2))*(KD) + (K0) + (c&3)*8, (char*)(LB) + (c & ~63)*16); \
    c = tid + 256; \
    gl2lds16((APTR) + (size_t)(m0 + (c>>2))*(KD) + (K0) + (c&3)*8, (char*)(LA) + (c & ~63)*16); \
    gl2lds16((BPTR) + (size_t)(n0 + (c>>2))*(KD) + (K0) + (c&3)*8, (char*)(LB) + (c & ~63)*16); }

#define GCOMP(LA, LB) { \
    const __hip_bfloat16* abase = (LA) + (mh + l16)*32 + quad*8; \
    const __hip_bfloat16* bbase = (LB) + (nh + l16)*32 + quad*8; \
    const short8 b0v = *(const short8*)(bbase); \
    const short8 b1v = *(const short8*)(bbase + 512); \
    const short8 b2v = *(const short8*)(bbase + 1024); \
    const short8 b3v = *(const short8*)(bbase + 1536); \
    GMROW(0) GMROW(1) GMROW(2) GMROW(3) }

#define GEMM_PIPE(APTR, BPTR, KD, KSTEPS) \
    GSTAGE(APTR, BPTR, KD, 0, ldsA0, ldsB0) \
    __syncthreads(); \
    _Pragma("unroll 1") \
    for (int kt = 0; kt < (KSTEPS); kt += 2) { \
        if (kt + 1 < (KSTEPS)) { GSTAGE(APTR, BPTR, KD, (kt+1)*32, ldsA1, ldsB1) } \
        GCOMP(ldsA0, ldsB0) \
        __syncthreads(); \
        if (kt + 1 < (KSTEPS)) { \
            if (kt + 2 < (KSTEPS)) { GSTAGE(APTR, BPTR, KD, (kt+2)*32, ldsA0, ldsB0) } \
            GCOMP(ldsA1, ldsB1) \
            __syncthreads(); \
        } \
    }

// GEMM1: h1 = GELU(feats @ w1 + b1) -> bf16, plus per-row (sum, sumsq) atomics.
#define G1EP(mf,nf) { \
    const int colv = n0 + nh + (nf)*16 + l16; \
    const float bv = bias[colv]; \
    f32x4 e; \
    e[0] = geluf(acc##mf##nf[0] + bv); e[1] = geluf(acc##mf##nf[1] + bv); \
    e[2] = geluf(acc##mf##nf[2] + bv); e[3] = geluf(acc##mf##nf[3] + bv); \
    const int rrow = m0 + mh + (mf)*16 + quad*4; \
    h1[(size_t)(rrow+0)*H2 + colv] = __float2bfloat16(e[0]); \
    h1[(size_t)(rrow+1)*H2 + colv] = __float2bfloat16(e[1]); \
    h1[(size_t)(rrow+2)*H2 + colv] = __float2bfloat16(e[2]); \
    h1[(size_t)(rrow+3)*H2 + colv] = __float2bfloat16(e[3]); \
    sum##mf += e; sq##mf += e*e; }

#define G1RED(mf) { \
    f32x4 s = sum##mf, q = sq##mf; \
    s += shfl4(s,1); q += shfl4(q,1); s += shfl4(s,2); q += shfl4(q,2); \
    s += shfl4(s,4); q += shfl4(q,4); s += shfl4(s,8); q += shfl4(q,8); \
    if (l16 == 0) { const int rrow = m0 + mh + (mf)*16 + quad*4; \
        atomicAdd(&stats[2*(rrow+0)],   s[0]); atomicAdd(&stats[2*(rrow+0)+1], q[0]); \
        atomicAdd(&stats[2*(rrow+1)],   s[1]); atomicAdd(&stats[2*(rrow+1)+1], q[1]); \
        atomicAdd(&stats[2*(rrow+2)],   s[2]); atomicAdd(&stats[2*(rrow+2)+1], q[2]); \
        atomicAdd(&stats[2*(rrow+3)],   s[3]); atomicAdd(&stats[2*(rrow+3)+1], q[3]); } }

__global__ __launch_bounds__(256) __attribute__((amdgpu_waves_per_eu(1, 4)))
void gemm1_kernel(const __hip_bfloat16* __restrict__ feats,
                  const __hip_bfloat16* __restrict__ w1T,
                  const float* __restrict__ bias,
                  __hip_bfloat16* __restrict__ h1,
                  float* __restrict__ stats) {
    __shared__ __align__(16) __hip_bfloat16 ldsA0[128 * 32];
    __shared__ __align__(16) __hip_bfloat16 ldsB0[128 * 32];
    __shared__ __align__(16) __hip_bfloat16 ldsA1[128 * 32];
    __shared__ __align__(16) __hip_bfloat16 ldsB1[128 * 32];
    const int tid  = threadIdx.x;
    const int wave = tid >> 6;
    const int lane = tid & 63;
    const int quad = lane >> 4;
    const int l16  = lane & 15;
    const int mh   = (wave >> 1) * 64;
    const int nh   = (wave & 1) * 64;
    const int m0   = blockIdx.x * 128;
    const int n0   = blockIdx.y * 128;
    GDECL
    GEMM_PIPE(feats, w1T, KPAD, 9)
    f32x4 sum0={0,0,0,0},sum1={0,0,0,0},sum2={0,0,0,0},sum3={0,0,0,0};
    f32x4 sq0={0,0,0,0},sq1={0,0,0,0},sq2={0,0,0,0},sq3={0,0,0,0};
    G1EP(0,0) G1EP(0,1) G1EP(0,2) G1EP(0,3)
    G1EP(1,0) G1EP(1,1) G1EP(1,2) G1EP(1,3)
    G1EP(2,0) G1EP(2,1) G1EP(2,2) G1EP(2,3)
    G1EP(3,0) G1EP(3,1) G1EP(3,2) G1EP(3,3)
    G1RED(0) G1RED(1) G1RED(2) G1RED(3)
}

// GEMM2: out = rstd_m*(h1 @ w2g - mu_m*gw[n]) + cvec[n]  (LN folded)
#define STATR(r) { const float su = stats[2*(rrow+(r))]; const float qu = stats[2*(rrow+(r))+1]; \
    const float m_ = su * (1.0f/512.0f); const float v_ = qu * (1.0f/512.0f) - m_*m_; \
    muv[r] = m_; rsv[r] = rsqrtf(v_ + 1e-5f); }

#define G2C(mf,nf) { const int colv = n0 + nh + (nf)*16 + l16; \
    const float g_ = gw[colv], c_ = cvec[colv]; \
    out[(size_t)(rrow+0)*HID + colv] = rsv[0]*(acc##mf##nf[0] - muv[0]*g_) + c_; \
    out[(size_t)(rrow+1)*HID + colv] = rsv[1]*(acc##mf##nf[1] - muv[1]*g_) + c_; \
    out[(size_t)(rrow+2)*HID + colv] = rsv[2]*(acc##mf##nf[2] - muv[2]*g_) + c_; \
    out[(size_t)(rrow+3)*HID + colv] = rsv[3]*(acc##mf##nf[3] - muv[3]*g_) + c_; }

#define G2EP(mf) { const int rrow = m0 + mh + (mf)*16 + quad*4; \
    f32x4 muv, rsv; \
    STATR(0) STATR(1) STATR(2) STATR(3) \
    G2C(mf,0) G2C(mf,1) G2C(mf,2) G2C(mf,3) }

__global__ __launch_bounds__(256) __attribute__((amdgpu_waves_per_eu(1, 4)))
void gemm2_kernel(const __hip_bfloat16* __restrict__ h1,
                  const __hip_bfloat16* __restrict__ w2g,
                  const float* __restrict__ stats,
                  const float* __restrict__ gw,
                  const float* __restrict__ cvec,
                  float* __restrict__ out) {
    __shared__ __align__(16) __hip_bfloat16 ldsA0[128 * 32];
    __shared__ __align__(16) __hip_bfloat16 ldsB0[128 * 32];
    __shared__ __align__(16) __hip_bfloat16 ldsA1[128 * 32];
    __shared__ __align__(16) __hip_bfloat16 ldsB1[128 * 32];
    const int tid  = threadIdx.x;
    const int wave = tid >> 6;
    const int lane = tid & 63;
    const int quad = lane >> 4;
    const int l16  = lane & 15;
    const int mh   = (wave >> 1) * 64;
    const int nh   = (wave & 1) * 64;
    const int m0   = blockIdx.x * 128;
    const int n0   = blockIdx.y * 128;
    GDECL
    GEMM_PIPE(h1, w2g, H2, 16)
    G2EP(0) G2EP(1) G2EP(2) G2EP(3)
}

// ============================================================================
extern "C" void kernel_launch(void* const* d_in, const int* in_sizes, int n_in,
                              void* d_out, int out_size, void* d_ws, size_t ws_size,
                              hipStream_t stream) {
    const float* x   = (const float*)d_in[0];
    const float* w1  = (const float*)d_in[1];
    const float* b1  = (const float*)d_in[2];
    const float* lng = (const float*)d_in[3];
    const float* lnb = (const float*)d_in[4];
    const float* w2  = (const float*)d_in[5];
    const float* b2  = (const float*)d_in[6];
    float* out = (float*)d_out;

    char* ws = (char*)d_ws;
    __hip_bfloat16* feats = (__hip_bfloat16*)(ws);                        // 9437184
    __hip_bfloat16* h1    = (__hip_bfloat16*)(ws + 9437184);              // 16777216
    __hip_bfloat16* w1T   = (__hip_bfloat16*)(ws + 26214400);             // 294912
    __hip_bfloat16* w2g   = (__hip_bfloat16*)(ws + 26509312);             // 262144
    float*          gw    = (float*)(ws + 26771456);                      // 4096
    float*          cvec  = (float*)(ws + 26775552);                      // 4096
    float*          stats = (float*)(ws + 26779648);                      // 131072

    prep_kernel<<<dim3(768), dim3(512), 0, stream>>>(w1, w2, lng, lnb, b2,
                                                     w1T, w2g, gw, cvec, stats);
    sig_kernel<<<dim3(8 * SBLK), dim3(192), 0, stream>>>(x, feats);
    gemm1_kernel<<<dim3(128, 4), dim3(256), 0, stream>>>(feats, w1T, b1, h1, stats);
    gemm2_kernel<<<dim3(128, 2), dim3(256), 0, stream>>>(h1, w2g, stats, gw, cvec, out);
}